// Round 8
// baseline (445.555 us; speedup 1.0000x reference)
//
#include <hip/hip_runtime.h>

// ---------------------------------------------------------------------------
// LinearAttention (Linformer-style) on MI355X, bf16 MFMA pipeline, f32 accum.
// B=4 S=4096 D=1024 H=16 R=256 DK=64
// Round 8: gemm_bt occupancy restructure — 256x128 tile, BK=32, 48KB LDS ->
//          2-3 blocks/CU co-resident (was 1). Merged phase, counted VMW3,
//          64B-row swizzle (2-way = free). Everything else unchanged.
// ---------------------------------------------------------------------------

typedef __bf16 bf16;
typedef bf16 bf16x8 __attribute__((ext_vector_type(8)));
typedef bf16 bf16x4 __attribute__((ext_vector_type(4)));
typedef float f32x4 __attribute__((ext_vector_type(4)));

constexpr int BB = 4, SS = 4096, DD = 1024, HH = 16, RR = 256, DK = 64;

// q-projection output pre-scale: logits*log2e/8 so softmax uses exp2 directly
#define QSCALE 0.1803368801111204f

// async global->LDS, 16B per lane. ldsbase must be wave-uniform; HW writes
// lane l's 16B at ldsbase + l*16. gptr is per-lane.
__device__ __forceinline__ void gl2lds16(const void* g, void* l, int lane)
{
#if __has_builtin(__builtin_amdgcn_global_load_lds)
    auto gp = reinterpret_cast<const __attribute__((address_space(1))) void*>(
        reinterpret_cast<uintptr_t>(g));
    auto lp = reinterpret_cast<__attribute__((address_space(3))) void*>(
        reinterpret_cast<uintptr_t>(l));
    __builtin_amdgcn_global_load_lds(gp, lp, 16, 0, 0);
    (void)lane;
#else
    *(bf16x8*)((char*)l + lane * 16) = *(const bf16x8*)g;
#endif
}

#define VMW3  asm volatile("s_waitcnt vmcnt(3)" ::: "memory")
#define VMW0  asm volatile("s_waitcnt vmcnt(0)" ::: "memory")
#define LGKM0 asm volatile("s_waitcnt lgkmcnt(0)" ::: "memory")

// ---------------------------------------------------------------------------
// Elementwise f32 -> bf16 convert, 8 elems/thread
// ---------------------------------------------------------------------------
__global__ void cvt_f32_bf16(const float* __restrict__ in, bf16* __restrict__ out, int n)
{
    int i = (blockIdx.x * 256 + threadIdx.x) * 8;
    if (i < n) {
        float4 v0 = *(const float4*)(in + i);
        float4 v1 = *(const float4*)(in + i + 4);
        bf16x8 h;
        h[0] = (bf16)v0.x; h[1] = (bf16)v0.y; h[2] = (bf16)v0.z; h[3] = (bf16)v0.w;
        h[4] = (bf16)v1.x; h[5] = (bf16)v1.y; h[6] = (bf16)v1.z; h[7] = (bf16)v1.w;
        *(bf16x8*)(out + i) = h;
    }
}

// ---------------------------------------------------------------------------
// Tiled transpose + convert: in[batch][rows][cols] f32 -> out[batch][cols][rows]
// bf16. 64x64 tiles, block (64,4).
// ---------------------------------------------------------------------------
__global__ void transpose_cvt(const float* __restrict__ in, bf16* __restrict__ out,
                              int rows, int cols)
{
    __shared__ float t[64][65];
    const float* I = in + (size_t)blockIdx.z * rows * cols;
    bf16* O = out + (size_t)blockIdx.z * rows * cols;
    int c0 = blockIdx.x * 64, r0 = blockIdx.y * 64;
    int tx = threadIdx.x, ty = threadIdx.y;
#pragma unroll
    for (int i = ty; i < 64; i += 4)
        t[i][tx] = I[(size_t)(r0 + i) * cols + c0 + tx];
    __syncthreads();
#pragma unroll
    for (int i = ty; i < 64; i += 4)
        O[(size_t)(c0 + i) * rows + r0 + tx] = (bf16)t[tx][i];
}

// ---------------------------------------------------------------------------
// C[M,N] = (A[M,K](bf16) * W[N,K]^T(bf16) + bias[N]) * oscale.   K == 1024.
// 256x128 tile, BK=32, 512 threads = 8 waves (4M x 2N), 64x64 per wave.
// LDS 48KB (As 2x16KB + Bs 2x8KB) -> 2-3 blocks/CU co-resident; independent
// blocks hide each other's barrier/vmcnt stalls.
// Per phase (1 phase per K-tile): 8 ds_read_b128 -> lgkm0 -> barrier ->
// stage tile t+2 (3 gload_lds, overwrites the buffer just read) -> VMW3
// (drains tile t+1; youngest drained load 1 full phase old) -> barrier ->
// 16 MFMA. Rows are 64B: read slot = g ^ (lr>>2); source col pre-swizzled
// (l&3)^((l>>4)&3) -> exactly 2 lanes/bank (free).
// ---------------------------------------------------------------------------
template <bool OUT_F32>
__global__ __launch_bounds__(512, 4) void gemm_bt(const bf16* __restrict__ A,
                                                  const bf16* __restrict__ W,
                                                  const float* __restrict__ bias,
                                                  void* __restrict__ Cp,
                                                  int M, int N, int K, float oscale)
{
    __shared__ bf16 As[2][256][32];
    __shared__ bf16 Bs[2][128][32];
    const int tid = threadIdx.x, wv = tid >> 6, lane = tid & 63;
    const int g = lane >> 4, lr = lane & 15;

    const int nwg = gridDim.x;
    const int cpx = nwg >> 3;                      // nwg % 8 == 0 (bijective)
    const int bid = blockIdx.x;
    const int swz = (bid & 7) * cpx + (bid >> 3);
    const int gx = N >> 7;
    const int mt = swz / gx, nt = swz % gx;
    const int m0 = mt * 256, n0 = nt * 128;
    const int wm = (wv >> 1) * 64, wn = (wv & 1) * 64;

    // staging: chunk = 16 rows x 32 bf16 (1024B); lane l -> row l>>2, slot l&3;
    // global source col pre-swizzled: col8 = (l&3) ^ ((l>>4)&3)
    const int srow = lane >> 2;
    const int scol = ((lane & 3) ^ ((lane >> 4) & 3)) * 8;

    f32x4 acc[4][4] = {};

    auto stageA = [&](int buf, int tk) {           // 16 chunks, 2 per wave
#pragma unroll
        for (int s2 = 0; s2 < 2; ++s2) {
            int c = wv * 2 + s2;
            gl2lds16(A + (size_t)(m0 + c * 16 + srow) * 1024 + tk * 32 + scol,
                     &As[buf][c * 16][0], lane);
        }
    };
    auto stageB = [&](int buf, int tk) {           // 8 chunks, 1 per wave
        gl2lds16(W + (size_t)(n0 + wv * 16 + srow) * 1024 + tk * 32 + scol,
                 &Bs[buf][wv * 16][0], lane);
    };

#define PHK(PB, STAGE_STMT, VM_STMT)                                             \
    {                                                                            \
        const int so = (g ^ (lr >> 2)) << 4;                                     \
        bf16x8 aF[4], bF[4];                                                     \
        _Pragma("unroll") for (int mm = 0; mm < 4; ++mm)                         \
            aF[mm] = *(const bf16x8*)((const char*)&As[PB][wm + mm * 16 + lr][0] + so); \
        _Pragma("unroll") for (int nn = 0; nn < 4; ++nn)                         \
            bF[nn] = *(const bf16x8*)((const char*)&Bs[PB][wn + nn * 16 + lr][0] + so); \
        LGKM0;                                                                   \
        __builtin_amdgcn_s_barrier();              /* all waves' reads done */   \
        STAGE_STMT;                                /* overwrite buffer PB */     \
        VM_STMT;                                   /* drain tile t+1 */          \
        __builtin_amdgcn_s_barrier();              /* next buffer visible */     \
        __builtin_amdgcn_sched_barrier(0);                                       \
        __builtin_amdgcn_s_setprio(1);                                           \
        _Pragma("unroll") for (int mm = 0; mm < 4; ++mm) {                       \
            _Pragma("unroll") for (int nn = 0; nn < 4; ++nn) {                   \
                acc[mm][nn] = __builtin_amdgcn_mfma_f32_16x16x32_bf16(           \
                    aF[mm], bF[nn], acc[mm][nn], 0, 0, 0); } }                   \
        __builtin_amdgcn_s_setprio(0);                                           \
    }

    // prologue: stage tiles 0,1 (6 loads); VMW3 drains tile 0, leaves tile 1
    stageA(0, 0); stageB(0, 0);
    stageA(1, 1); stageB(1, 1);
    VMW3;
    __builtin_amdgcn_s_barrier();

#pragma unroll 1
    for (int t = 0; t < 30; ++t) {                 // tiles 0..29 (K/32 = 32)
        const int pb = t & 1;
        PHK(pb, { stageA(pb, t + 2); stageB(pb, t + 2); }, VMW3);
    }
    PHK(0, (void)0, VMW0);                         // tile 30
    PHK(1, (void)0, (void)0);                      // tile 31
#undef PHK

    float bv[4];
#pragma unroll
    for (int n = 0; n < 4; ++n) bv[n] = bias[n0 + wn + n * 16 + lr];

    if constexpr (OUT_F32) {
#pragma unroll
        for (int n = 0; n < 4; ++n) {
            int col = n0 + wn + n * 16 + lr;
#pragma unroll
            for (int m = 0; m < 4; ++m) {
                int row = m0 + wm + m * 16 + 4 * g;
#pragma unroll
                for (int i = 0; i < 4; ++i)
                    ((float*)Cp)[(size_t)(row + i) * N + col] = (acc[m][n][i] + bv[n]) * oscale;
            }
        }
    } else {
        // bounce through LDS (swizzled, 4KB/wave in As) -> 16B coalesced stores,
        // done in two 32-row halves
        char* myb = (char*)&As[0][0][0] + wv * 4096;
#pragma unroll
        for (int mh = 0; mh < 2; ++mh) {
#pragma unroll
            for (int mm = 0; mm < 2; ++mm)
#pragma unroll
                for (int n = 0; n < 4; ++n) {
                    int colb = (n * 16 + lr) * 2;
#pragma unroll
                    for (int i = 0; i < 4; ++i) {
                        int row = mm * 16 + 4 * g + i;
                        *(bf16*)(myb + row * 128 + (colb ^ ((row & 7) << 4))) =
                            (bf16)((acc[mh * 2 + mm][n][i] + bv[n]) * oscale);
                    }
                }
            __builtin_amdgcn_wave_barrier();
            bf16* Cb = (bf16*)Cp + (size_t)(m0 + wm + mh * 32) * N + n0 + wn;
#pragma unroll
            for (int it = 0; it < 4; ++it) {
                int r = it * 8 + (lane >> 3);
                int sl = lane & 7;
                bf16x8 vv = *(const bf16x8*)(myb + r * 128 + ((sl ^ (r & 7)) << 4));
                *(bf16x8*)(Cb + (size_t)r * N + sl * 8) = vv;
            }
            __builtin_amdgcn_wave_barrier();
        }
    }
}

// ---------------------------------------------------------------------------
// kp[b,h,d,r] += sum_{s in chunk} X[b,s,h*64+d] * P[h,r,s]
// ---------------------------------------------------------------------------
__global__ __launch_bounds__(256) void kpvp_gemm(const bf16* __restrict__ X,
                                                 const bf16* __restrict__ P,
                                                 float* __restrict__ out)
{
    __shared__ bf16 Ak[64][40];
    __shared__ bf16 Bs[256][32];
    const int b = blockIdx.z, h = blockIdx.y;
    const int s0 = blockIdx.x * 512;
    const int tid = threadIdx.x, wv = tid >> 6, lane = tid & 63;
    const int g = lane >> 4, lr = lane & 15;
    const int lrow = lane >> 2, lcol = (lane & 3) * 8;
    const bf16* Pg = P + ((size_t)h * RR + wv * 64 + lrow) * SS + lcol;
    f32x4 acc[4][4] = {};

    for (int kt = 0; kt < 512; kt += 32) {
        const int sb = s0 + kt;
        __syncthreads();
#pragma unroll
        for (int j = 0; j < 4; ++j)
            gl2lds16(Pg + (size_t)(j * 16) * SS + sb, &Bs[wv * 64 + j * 16][0], lane);
        {
            int sl = tid >> 3, dblk = (tid & 7) * 8;
            bf16x8 v = *(const bf16x8*)(X + ((size_t)b * SS + sb + sl) * DD + h * DK + dblk);
#pragma unroll
            for (int j = 0; j < 8; ++j) Ak[dblk + j][sl] = v[j];
        }
        __syncthreads();

        bf16x8 a[4], bb[4];
#pragma unroll
        for (int m = 0; m < 4; ++m) a[m] = *(const bf16x8*)&Ak[m * 16 + lr][g * 8];
#pragma unroll
        for (int n = 0; n < 4; ++n) bb[n] = *(const bf16x8*)&Bs[wv * 64 + n * 16 + lr][g * 8];
#pragma unroll
        for (int m = 0; m < 4; ++m)
#pragma unroll
            for (int n = 0; n < 4; ++n)
                acc[m][n] = __builtin_amdgcn_mfma_f32_16x16x32_bf16(a[m], bb[n], acc[m][n], 0, 0, 0);
    }

    float* o = out + ((size_t)(b * HH + h)) * DK * RR;
#pragma unroll
    for (int m = 0; m < 4; ++m)
#pragma unroll
        for (int n = 0; n < 4; ++n) {
            int r = wv * 64 + n * 16 + lr;
#pragma unroll
            for (int i = 0; i < 4; ++i)
                atomicAdd(o + (size_t)(m * 16 + 4 * g + i) * RR + r, acc[m][n][i]);
        }
}

// ---------------------------------------------------------------------------
// Fused attention (round-2 version, verified): 256 blocks x 8 waves,
// KP/VP staged once, barrier-free inner loop, exp2 softmax, deferred norm.
// ---------------------------------------------------------------------------
__global__ __launch_bounds__(512) void attn_fused(const bf16* __restrict__ qb,
                                                  const bf16* __restrict__ kpt,
                                                  const bf16* __restrict__ vpb,
                                                  bf16* __restrict__ ctx)
{
    __shared__ bf16 KPs[256][72];      // kpT tile [r][d]
    __shared__ bf16 VPs[64][264];      // vp tile [d][r]
    __shared__ bf16 Ps[8][16][264];    // per-wave P / out-bounce tile
    const int b = blockIdx.z, h = blockIdx.y, qt = blockIdx.x;
    const int tid = threadIdx.x, wv = tid >> 6, lane = tid & 63;
    const int g = lane >> 4, lr = lane & 15;
    const bf16* kph = kpt + ((size_t)(b * HH + h)) * RR * DK;
    const bf16* vph = vpb + ((size_t)(b * HH + h)) * DK * RR;

#pragma unroll
    for (int p = 0; p < 4; ++p) {
        int f = p * 512 + tid;
        *(bf16x8*)&KPs[f >> 3][(f & 7) * 8] = *(const bf16x8*)(kph + (size_t)f * 8);
        *(bf16x8*)&VPs[f >> 5][(f & 31) * 8] = *(const bf16x8*)(vph + (size_t)f * 8);
    }

    const bf16* qbase = qb + (size_t)b * SS * DD + h * DK;
    int row0 = qt * 1024 + wv * 16;
    bf16x8 aq0 = *(const bf16x8*)(qbase + (size_t)(row0 + lr) * DD + g * 8);
    bf16x8 aq1 = *(const bf16x8*)(qbase + (size_t)(row0 + lr) * DD + 32 + g * 8);
    __syncthreads();

    for (int it = 0; it < 8; ++it) {
        f32x4 acc[16] = {};
        __builtin_amdgcn_s_setprio(1);
#pragma unroll
        for (int nf = 0; nf < 16; ++nf) {
            bf16x8 b0 = *(const bf16x8*)&KPs[nf * 16 + lr][g * 8];
            bf16x8 b1 = *(const bf16x8*)&KPs[nf * 16 + lr][32 + g * 8];
            acc[nf] = __builtin_amdgcn_mfma_f32_16x16x32_bf16(aq0, b0, acc[nf], 0, 0, 0);
            acc[nf] = __builtin_amdgcn_mfma_f32_16x16x32_bf16(aq1, b1, acc[nf], 0, 0, 0);
        }
        __builtin_amdgcn_s_setprio(0);

        bf16x8 aqn0 = aq0, aqn1 = aq1;
        if (it < 7) {
            const bf16* qr = qbase + (size_t)(row0 + 128 + lr) * DD;
            aqn0 = *(const bf16x8*)(qr + g * 8);
            aqn1 = *(const bf16x8*)(qr + 32 + g * 8);
        }

        float rs[4];
#pragma unroll
        for (int i = 0; i < 4; ++i) {
            float s = 0.f;
#pragma unroll
            for (int nf = 0; nf < 16; ++nf) {
                float pv = exp2f(acc[nf][i]);
                acc[nf][i] = pv;
                s += pv;
            }
#pragma unroll
            for (int msk = 1; msk < 16; msk <<= 1) s += __shfl_xor(s, msk, 64);
            rs[i] = 1.f / s;
        }

#pragma unroll
        for (int nf = 0; nf < 16; ++nf)
#pragma unroll
            for (int i = 0; i < 4; ++i)
                Ps[wv][4 * g + i][nf * 16 + lr] = (bf16)acc[nf][i];
        __builtin_amdgcn_wave_barrier();

        f32x4 o[4] = {};
        __builtin_amdgcn_s_setprio(1);
#pragma unroll
        for (int ks = 0; ks < 8; ++ks) {
            bf16x8 pa = *(const bf16x8*)&Ps[wv][lr][ks * 32 + g * 8];
#pragma unroll
            for (int n = 0; n < 4; ++n) {
                bf16x8 vb = *(const bf16x8*)&VPs[n * 16 + lr][ks * 32 + g * 8];
                o[n] = __builtin_amdgcn_mfma_f32_16x16x32_bf16(pa, vb, o[n], 0, 0, 0);
            }
        }
        __builtin_amdgcn_s_setprio(0);
        __builtin_amdgcn_wave_barrier();

#pragma unroll
        for (int n = 0; n < 4; ++n)
#pragma unroll
            for (int i = 0; i < 4; ++i)
                Ps[wv][4 * g + i][n * 16 + lr] = (bf16)(o[n][i] * rs[i]);
        __builtin_amdgcn_wave_barrier();
        bf16* crow = ctx + (size_t)(b * SS + row0) * DD + h * DK;
#pragma unroll
        for (int p = 0; p < 2; ++p) {
            int r = p * 8 + (lane >> 3), c = (lane & 7) * 8;
            bf16x8 ov = *(const bf16x8*)&Ps[wv][r][c];
            *(bf16x8*)(crow + (size_t)r * DD + c) = ov;
        }
        __builtin_amdgcn_wave_barrier();

        aq0 = aqn0; aq1 = aqn1;
        row0 += 128;
    }
}

// ---------------------------------------------------------------------------
extern "C" void kernel_launch(void* const* d_in, const int* in_sizes, int n_in,
                              void* d_out, int out_size, void* d_ws, size_t ws_size,
                              hipStream_t stream)
{
    const float* query = (const float*)d_in[0];
    const float* key   = (const float*)d_in[1];
    const float* value = (const float*)d_in[2];
    const float* Wq = (const float*)d_in[3];  const float* bq = (const float*)d_in[4];
    const float* Wk = (const float*)d_in[5];  const float* bk = (const float*)d_in[6];
    const float* Wv = (const float*)d_in[7];  const float* bv = (const float*)d_in[8];
    const float* Wo = (const float*)d_in[9];  const float* bo = (const float*)d_in[10];
    const float* E  = (const float*)d_in[11];
    const float* F  = (const float*)d_in[12];

    char* w = (char*)d_ws;
    size_t off = 0;
    auto alloc = [&](size_t bytes) -> char* {
        char* p = w + off;
        off += (bytes + 255) & ~(size_t)255;
        return p;
    };

    const size_t DW   = (size_t)DD * DD;           // 1M
    const size_t BSD  = (size_t)BB * SS * DD;      // 16.78M
    const size_t HRS  = (size_t)HH * RR * SS;      // 16.78M
    const size_t BHDR = (size_t)BB * HH * DK * RR; // 4.19M

    bf16* wqb = (bf16*)alloc(DW * 2);
    bf16* wkb = (bf16*)alloc(DW * 2);
    bf16* wvb = (bf16*)alloc(DW * 2);
    bf16* wob = (bf16*)alloc(DW * 2);
    bf16* ebt = (bf16*)alloc(HRS * 2);             // E^T [H,R,S]
    bf16* fbt = (bf16*)alloc(HRS * 2);             // F^T [H,R,S]
    bf16* qin = (bf16*)alloc(BSD * 2);             // bf16 inputs; later reused:
    bf16* kin = (bf16*)alloc(BSD * 2);             //   qin -> kpf/vpf, kin -> kpt/vp,
    bf16* vin = (bf16*)alloc(BSD * 2);             //   vin -> ctx
    bf16* qbuf = (bf16*)alloc(BSD * 2);
    bf16* kbuf = (bf16*)alloc(BSD * 2);
    bf16* vbuf = (bf16*)alloc(BSD * 2);
    if (off > ws_size) return;

    // aliased scratch (stream-ordered reuse; regions dead by first write)
    float* kpf  = (float*)qin;                     // BHDR f32
    float* vpf  = kpf + BHDR;                      // BHDR f32
    bf16*  kpt  = (bf16*)kin;                      // BHDR bf16 [B,H,R,DK]
    bf16*  vpbb = kpt + BHDR;                      // BHDR bf16 [B,H,DK,R]
    bf16*  ctx  = (bf16*)vin;                      // BSD bf16

    // 1. converts: weights + activations
    cvt_f32_bf16<<<(int)(DW / 2048), 256, 0, stream>>>(Wq, wqb, (int)DW);
    cvt_f32_bf16<<<(int)(DW / 2048), 256, 0, stream>>>(Wk, wkb, (int)DW);
    cvt_f32_bf16<<<(int)(DW / 2048), 256, 0, stream>>>(Wv, wvb, (int)DW);
    cvt_f32_bf16<<<(int)(DW / 2048), 256, 0, stream>>>(Wo, wob, (int)DW);
    cvt_f32_bf16<<<(int)(BSD / 2048), 256, 0, stream>>>(query, qin, (int)BSD);
    cvt_f32_bf16<<<(int)(BSD / 2048), 256, 0, stream>>>(key,   kin, (int)BSD);
    cvt_f32_bf16<<<(int)(BSD / 2048), 256, 0, stream>>>(value, vin, (int)BSD);

    // 2. E,F transpose+convert: [H,S,R] -> [H,R,S] (64x64 tiles)
    dim3 tb(64, 4);
    transpose_cvt<<<dim3(RR / 64, SS / 64, HH), tb, 0, stream>>>(E, ebt, SS, RR);
    transpose_cvt<<<dim3(RR / 64, SS / 64, HH), tb, 0, stream>>>(F, fbt, SS, RR);

    // 3. QKV projections (256x128 co-resident GEMM; q pre-scaled for exp2)
    const int nwg = ((BB * SS) / 256) * (DD / 128);   // 64*8 = 512, % 8 == 0
    gemm_bt<false><<<nwg, 512, 0, stream>>>(qin, wqb, bq, qbuf, BB * SS, DD, DD, QSCALE);
    gemm_bt<false><<<nwg, 512, 0, stream>>>(kin, wkb, bk, kbuf, BB * SS, DD, DD, 1.0f);
    gemm_bt<false><<<nwg, 512, 0, stream>>>(vin, wvb, bv, vbuf, BB * SS, DD, DD, 1.0f);

    // 4. kp/vp = k^T E, v^T F  (qin region now dead -> kpf/vpf)
    hipMemsetAsync(kpf, 0, BHDR * 4 * 2, stream);
    kpvp_gemm<<<dim3(SS / 512, HH, BB), 256, 0, stream>>>(kbuf, ebt, kpf);
    kpvp_gemm<<<dim3(SS / 512, HH, BB), 256, 0, stream>>>(vbuf, fbt, vpf);

    // 5. kp -> kpT bf16 [B,H,R,DK]; vp -> bf16 [B,H,DK,R]  (kin region dead)
    transpose_cvt<<<dim3(RR / 64, DK / 64, BB * HH), tb, 0, stream>>>(kpf, kpt, DK, RR);
    cvt_f32_bf16<<<(int)(BHDR / 2048), 256, 0, stream>>>(vpf, vpbb, (int)BHDR);

    // 6. fused softmax attention (vin region dead -> ctx)
    attn_fused<<<dim3(SS / 1024, HH, BB), 512, 0, stream>>>(qbuf, kpt, vpbb, ctx);

    // 7. output projection -> f32 d_out
    gemm_bt<true><<<nwg, 512, 0, stream>>>(ctx, wob, bo, d_out, BB * SS, DD, DD, 1.0f);
}

// Round 9
// 387.666 us; speedup vs baseline: 1.1493x; 1.1493x over previous
//
#include <hip/hip_runtime.h>

// ---------------------------------------------------------------------------
// LinearAttention (Linformer-style) on MI355X, bf16 MFMA pipeline, f32 accum.
// B=4 S=4096 D=1024 H=16 R=256 DK=64
// Round 9: (1) kpvp reads E/F f32 directly as B-fragments (fused
//          transpose+convert; E/F transpose kernels deleted);
//          (2) attn 2-deep pipeline: QK(it+1) MFMAs issued before softmax(it)
//          (static pA/pB accumulators), q prefetch distance 2.
//          gemm_bt frozen at round-8 (all dispatches measured <56us).
// ---------------------------------------------------------------------------

typedef __bf16 bf16;
typedef bf16 bf16x8 __attribute__((ext_vector_type(8)));
typedef bf16 bf16x4 __attribute__((ext_vector_type(4)));
typedef float f32x4 __attribute__((ext_vector_type(4)));

constexpr int BB = 4, SS = 4096, DD = 1024, HH = 16, RR = 256, DK = 64;

// q-projection output pre-scale: logits*log2e/8 so softmax uses exp2 directly
#define QSCALE 0.1803368801111204f

// async global->LDS, 16B per lane. ldsbase must be wave-uniform; HW writes
// lane l's 16B at ldsbase + l*16. gptr is per-lane.
__device__ __forceinline__ void gl2lds16(const void* g, void* l, int lane)
{
#if __has_builtin(__builtin_amdgcn_global_load_lds)
    auto gp = reinterpret_cast<const __attribute__((address_space(1))) void*>(
        reinterpret_cast<uintptr_t>(g));
    auto lp = reinterpret_cast<__attribute__((address_space(3))) void*>(
        reinterpret_cast<uintptr_t>(l));
    __builtin_amdgcn_global_load_lds(gp, lp, 16, 0, 0);
    (void)lane;
#else
    *(bf16x8*)((char*)l + lane * 16) = *(const bf16x8*)g;
#endif
}

#define VMW3  asm volatile("s_waitcnt vmcnt(3)" ::: "memory")
#define VMW0  asm volatile("s_waitcnt vmcnt(0)" ::: "memory")
#define LGKM0 asm volatile("s_waitcnt lgkmcnt(0)" ::: "memory")

// ---------------------------------------------------------------------------
// Elementwise f32 -> bf16 convert, 8 elems/thread
// ---------------------------------------------------------------------------
__global__ void cvt_f32_bf16(const float* __restrict__ in, bf16* __restrict__ out, int n)
{
    int i = (blockIdx.x * 256 + threadIdx.x) * 8;
    if (i < n) {
        float4 v0 = *(const float4*)(in + i);
        float4 v1 = *(const float4*)(in + i + 4);
        bf16x8 h;
        h[0] = (bf16)v0.x; h[1] = (bf16)v0.y; h[2] = (bf16)v0.z; h[3] = (bf16)v0.w;
        h[4] = (bf16)v1.x; h[5] = (bf16)v1.y; h[6] = (bf16)v1.z; h[7] = (bf16)v1.w;
        *(bf16x8*)(out + i) = h;
    }
}

// ---------------------------------------------------------------------------
// Tiled transpose + convert (still used for kp f32 [DK,R] -> kpT bf16 [R,DK])
// ---------------------------------------------------------------------------
__global__ void transpose_cvt(const float* __restrict__ in, bf16* __restrict__ out,
                              int rows, int cols)
{
    __shared__ float t[64][65];
    const float* I = in + (size_t)blockIdx.z * rows * cols;
    bf16* O = out + (size_t)blockIdx.z * rows * cols;
    int c0 = blockIdx.x * 64, r0 = blockIdx.y * 64;
    int tx = threadIdx.x, ty = threadIdx.y;
#pragma unroll
    for (int i = ty; i < 64; i += 4)
        t[i][tx] = I[(size_t)(r0 + i) * cols + c0 + tx];
    __syncthreads();
#pragma unroll
    for (int i = ty; i < 64; i += 4)
        O[(size_t)(c0 + i) * rows + r0 + tx] = (bf16)t[tx][i];
}

// ---------------------------------------------------------------------------
// C[M,N] = (A[M,K](bf16) * W[N,K]^T(bf16) + bias[N]) * oscale.   K == 1024.
// Round-8 structure (frozen): 256x128 tile, BK=32, 8 waves (4M x 2N), 48KB LDS
// -> co-resident blocks; counted VMW3; 64B-row swizzle.
// ---------------------------------------------------------------------------
template <bool OUT_F32>
__global__ __launch_bounds__(512, 4) void gemm_bt(const bf16* __restrict__ A,
                                                  const bf16* __restrict__ W,
                                                  const float* __restrict__ bias,
                                                  void* __restrict__ Cp,
                                                  int M, int N, int K, float oscale)
{
    __shared__ bf16 As[2][256][32];
    __shared__ bf16 Bs[2][128][32];
    const int tid = threadIdx.x, wv = tid >> 6, lane = tid & 63;
    const int g = lane >> 4, lr = lane & 15;

    const int nwg = gridDim.x;
    const int cpx = nwg >> 3;                      // nwg % 8 == 0 (bijective)
    const int bid = blockIdx.x;
    const int swz = (bid & 7) * cpx + (bid >> 3);
    const int gx = N >> 7;
    const int mt = swz / gx, nt = swz % gx;
    const int m0 = mt * 256, n0 = nt * 128;
    const int wm = (wv >> 1) * 64, wn = (wv & 1) * 64;

    const int srow = lane >> 2;
    const int scol = ((lane & 3) ^ ((lane >> 4) & 3)) * 8;

    f32x4 acc[4][4] = {};

    auto stageA = [&](int buf, int tk) {
#pragma unroll
        for (int s2 = 0; s2 < 2; ++s2) {
            int c = wv * 2 + s2;
            gl2lds16(A + (size_t)(m0 + c * 16 + srow) * 1024 + tk * 32 + scol,
                     &As[buf][c * 16][0], lane);
        }
    };
    auto stageB = [&](int buf, int tk) {
        gl2lds16(W + (size_t)(n0 + wv * 16 + srow) * 1024 + tk * 32 + scol,
                 &Bs[buf][wv * 16][0], lane);
    };

#define PHK(PB, STAGE_STMT, VM_STMT)                                             \
    {                                                                            \
        const int so = (g ^ (lr >> 2)) << 4;                                     \
        bf16x8 aF[4], bF[4];                                                     \
        _Pragma("unroll") for (int mm = 0; mm < 4; ++mm)                         \
            aF[mm] = *(const bf16x8*)((const char*)&As[PB][wm + mm * 16 + lr][0] + so); \
        _Pragma("unroll") for (int nn = 0; nn < 4; ++nn)                         \
            bF[nn] = *(const bf16x8*)((const char*)&Bs[PB][wn + nn * 16 + lr][0] + so); \
        LGKM0;                                                                   \
        __builtin_amdgcn_s_barrier();              /* all waves' reads done */   \
        STAGE_STMT;                                /* overwrite buffer PB */     \
        VM_STMT;                                   /* drain tile t+1 */          \
        __builtin_amdgcn_s_barrier();              /* next buffer visible */     \
        __builtin_amdgcn_sched_barrier(0);                                       \
        __builtin_amdgcn_s_setprio(1);                                           \
        _Pragma("unroll") for (int mm = 0; mm < 4; ++mm) {                       \
            _Pragma("unroll") for (int nn = 0; nn < 4; ++nn) {                   \
                acc[mm][nn] = __builtin_amdgcn_mfma_f32_16x16x32_bf16(           \
                    aF[mm], bF[nn], acc[mm][nn], 0, 0, 0); } }                   \
        __builtin_amdgcn_s_setprio(0);                                           \
    }

    stageA(0, 0); stageB(0, 0);
    stageA(1, 1); stageB(1, 1);
    VMW3;
    __builtin_amdgcn_s_barrier();

#pragma unroll 1
    for (int t = 0; t < 30; ++t) {
        const int pb = t & 1;
        PHK(pb, { stageA(pb, t + 2); stageB(pb, t + 2); }, VMW3);
    }
    PHK(0, (void)0, VMW0);
    PHK(1, (void)0, (void)0);
#undef PHK

    float bv[4];
#pragma unroll
    for (int n = 0; n < 4; ++n) bv[n] = bias[n0 + wn + n * 16 + lr];

    if constexpr (OUT_F32) {
#pragma unroll
        for (int n = 0; n < 4; ++n) {
            int col = n0 + wn + n * 16 + lr;
#pragma unroll
            for (int m = 0; m < 4; ++m) {
                int row = m0 + wm + m * 16 + 4 * g;
#pragma unroll
                for (int i = 0; i < 4; ++i)
                    ((float*)Cp)[(size_t)(row + i) * N + col] = (acc[m][n][i] + bv[n]) * oscale;
            }
        }
    } else {
        char* myb = (char*)&As[0][0][0] + wv * 4096;
#pragma unroll
        for (int mh = 0; mh < 2; ++mh) {
#pragma unroll
            for (int mm = 0; mm < 2; ++mm)
#pragma unroll
                for (int n = 0; n < 4; ++n) {
                    int colb = (n * 16 + lr) * 2;
#pragma unroll
                    for (int i = 0; i < 4; ++i) {
                        int row = mm * 16 + 4 * g + i;
                        *(bf16*)(myb + row * 128 + (colb ^ ((row & 7) << 4))) =
                            (bf16)((acc[mh * 2 + mm][n][i] + bv[n]) * oscale);
                    }
                }
            __builtin_amdgcn_wave_barrier();
            bf16* Cb = (bf16*)Cp + (size_t)(m0 + wm + mh * 32) * N + n0 + wn;
#pragma unroll
            for (int it = 0; it < 4; ++it) {
                int r = it * 8 + (lane >> 3);
                int sl = lane & 7;
                bf16x8 vv = *(const bf16x8*)(myb + r * 128 + ((sl ^ (r & 7)) << 4));
                *(bf16x8*)(Cb + (size_t)r * N + sl * 8) = vv;
            }
            __builtin_amdgcn_wave_barrier();
        }
    }
}

// ---------------------------------------------------------------------------
// kp[b,h,d,r] += sum_{s in chunk} X[b,s,h*64+d] * E[h,s,r]
// E read DIRECTLY as f32 [H,S,R] (B-fragment col=r is contiguous-in-r);
// fused transpose+convert in registers. A (X) reg-transposed to LDS as before.
// ---------------------------------------------------------------------------
__global__ __launch_bounds__(256) void kpvp_gemm(const bf16* __restrict__ X,
                                                 const float* __restrict__ E,
                                                 float* __restrict__ out)
{
    __shared__ bf16 Ak[64][40];
    const int b = blockIdx.z, h = blockIdx.y;
    const int s0 = blockIdx.x * 512;
    const int tid = threadIdx.x, wv = tid >> 6, lane = tid & 63;
    const int g = lane >> 4, lr = lane & 15;
    const float* Eh = E + (size_t)h * SS * RR;
    const int rbase = wv * 64 + lr;
    f32x4 acc[4][4] = {};

    for (int kt = 0; kt < 512; kt += 32) {
        const int sb = s0 + kt;
        __syncthreads();
        // B-fragments: E[h][sb + g*8 + j][rbase + n*16], f32 -> bf16 in regs.
        // Lanes lr=0..15 read 16 consecutive f32 (64B) per (g,n,j): coalesced.
        float ef[4][8];
        const float* Eb = Eh + (size_t)(sb + g * 8) * RR + rbase;
#pragma unroll
        for (int n = 0; n < 4; ++n)
#pragma unroll
            for (int j = 0; j < 8; ++j)
                ef[n][j] = Eb[(size_t)j * RR + n * 16];
        {   // A-stage with transpose: X[b, sb+sl, h*64+dblk+j] -> Ak[dblk+j][sl]
            int sl = tid >> 3, dblk = (tid & 7) * 8;
            bf16x8 v = *(const bf16x8*)(X + ((size_t)b * SS + sb + sl) * DD + h * DK + dblk);
#pragma unroll
            for (int j = 0; j < 8; ++j) Ak[dblk + j][sl] = v[j];
        }
        bf16x8 bb[4];
#pragma unroll
        for (int n = 0; n < 4; ++n)
#pragma unroll
            for (int j = 0; j < 8; ++j)
                bb[n][j] = (bf16)ef[n][j];
        __syncthreads();

        bf16x8 a[4];
#pragma unroll
        for (int m = 0; m < 4; ++m) a[m] = *(const bf16x8*)&Ak[m * 16 + lr][g * 8];
#pragma unroll
        for (int m = 0; m < 4; ++m)
#pragma unroll
            for (int n = 0; n < 4; ++n)
                acc[m][n] = __builtin_amdgcn_mfma_f32_16x16x32_bf16(a[m], bb[n], acc[m][n], 0, 0, 0);
    }

    float* o = out + ((size_t)(b * HH + h)) * DK * RR;
#pragma unroll
    for (int m = 0; m < 4; ++m)
#pragma unroll
        for (int n = 0; n < 4; ++n) {
            int r = wv * 64 + n * 16 + lr;
#pragma unroll
            for (int i = 0; i < 4; ++i)
                atomicAdd(o + (size_t)(m * 16 + 4 * g + i) * RR + r, acc[m][n][i]);
        }
}

// ---------------------------------------------------------------------------
// Fused attention v3: 2-deep pipeline. Per iter: QK(it+1) MFMAs (into the
// OTHER statically-named accumulator) issued BEFORE softmax(it) so the MFMA
// pipe fills while the VALU runs exp2/shfl. q prefetch distance = 2 iters.
// 256 blocks x 8 waves, KP/VP staged once, exp2 softmax, deferred norm.
// ---------------------------------------------------------------------------
__global__ __launch_bounds__(512) void attn_fused(const bf16* __restrict__ qb,
                                                  const bf16* __restrict__ kpt,
                                                  const bf16* __restrict__ vpb,
                                                  bf16* __restrict__ ctx)
{
    __shared__ bf16 KPs[256][72];      // kpT tile [r][d]
    __shared__ bf16 VPs[64][264];      // vp tile [d][r]
    __shared__ bf16 Ps[8][16][264];    // per-wave P / out-bounce tile
    const int b = blockIdx.z, h = blockIdx.y, qt = blockIdx.x;
    const int tid = threadIdx.x, wv = tid >> 6, lane = tid & 63;
    const int g = lane >> 4, lr = lane & 15;
    const bf16* kph = kpt + ((size_t)(b * HH + h)) * RR * DK;
    const bf16* vph = vpb + ((size_t)(b * HH + h)) * DK * RR;

#pragma unroll
    for (int p = 0; p < 4; ++p) {
        int f = p * 512 + tid;
        *(bf16x8*)&KPs[f >> 3][(f & 7) * 8] = *(const bf16x8*)(kph + (size_t)f * 8);
        *(bf16x8*)&VPs[f >> 5][(f & 31) * 8] = *(const bf16x8*)(vph + (size_t)f * 8);
    }

    const bf16* qbase = qb + (size_t)b * SS * DD + h * DK;
    const int row0 = qt * 1024 + wv * 16;

    // q for it=0
    bf16x8 qa0 = *(const bf16x8*)(qbase + (size_t)(row0 + lr) * DD + g * 8);
    bf16x8 qa1 = *(const bf16x8*)(qbase + (size_t)(row0 + lr) * DD + 32 + g * 8);
    __syncthreads();

    f32x4 pA[16] = {}, pB[16] = {};
    // prologue: QK(it=0) into pA
#pragma unroll
    for (int nf = 0; nf < 16; ++nf) {
        bf16x8 b0 = *(const bf16x8*)&KPs[nf * 16 + lr][g * 8];
        bf16x8 b1 = *(const bf16x8*)&KPs[nf * 16 + lr][32 + g * 8];
        pA[nf] = __builtin_amdgcn_mfma_f32_16x16x32_bf16(qa0, b0, pA[nf], 0, 0, 0);
        pA[nf] = __builtin_amdgcn_mfma_f32_16x16x32_bf16(qa1, b1, pA[nf], 0, 0, 0);
    }
    // q for it=1
    {
        const bf16* qr = qbase + (size_t)(row0 + 128 + lr) * DD;
        qa0 = *(const bf16x8*)(qr + g * 8);
        qa1 = *(const bf16x8*)(qr + 32 + g * 8);
    }

#define AITER(PC, PN, IT)                                                        \
    {                                                                            \
        /* prefetch q for IT+2 */                                                \
        bf16x8 qn0 = qa0, qn1 = qa1;                                             \
        if ((IT) < 6) {                                                          \
            const bf16* qr = qbase + (size_t)(row0 + ((IT) + 2) * 128 + lr) * DD;\
            qn0 = *(const bf16x8*)(qr + g * 8);                                  \
            qn1 = *(const bf16x8*)(qr + 32 + g * 8);                             \
        }                                                                        \
        /* QK(IT+1) into PN (qa holds q for IT+1) — overlaps softmax VALU */     \
        if ((IT) < 7) {                                                          \
            _Pragma("unroll") for (int nf = 0; nf < 16; ++nf) {                  \
                bf16x8 b0 = *(const bf16x8*)&KPs[nf * 16 + lr][g * 8];           \
                bf16x8 b1 = *(const bf16x8*)&KPs[nf * 16 + lr][32 + g * 8];      \
                PN[nf] = __builtin_amdgcn_mfma_f32_16x16x32_bf16(qa0, b0, PN[nf], 0, 0, 0); \
                PN[nf] = __builtin_amdgcn_mfma_f32_16x16x32_bf16(qa1, b1, PN[nf], 0, 0, 0); \
            }                                                                    \
        }                                                                        \
        /* softmax on PC */                                                      \
        float rs[4];                                                             \
        _Pragma("unroll") for (int i = 0; i < 4; ++i) {                          \
            float s = 0.f;                                                       \
            _Pragma("unroll") for (int nf = 0; nf < 16; ++nf) {                  \
                float pv = exp2f(PC[nf][i]);                                     \
                PC[nf][i] = pv;                                                  \
                s += pv;                                                         \
            }                                                                    \
            _Pragma("unroll") for (int msk = 1; msk < 16; msk <<= 1)             \
                s += __shfl_xor(s, msk, 64);                                     \
            rs[i] = 1.f / s;                                                     \
        }                                                                        \
        _Pragma("unroll") for (int nf = 0; nf < 16; ++nf)                        \
            _Pragma("unroll") for (int i = 0; i < 4; ++i)                        \
                Ps[wv][4 * g + i][nf * 16 + lr] = (bf16)PC[nf][i];               \
        __builtin_amdgcn_wave_barrier();                                         \
        f32x4 o[4] = {};                                                         \
        __builtin_amdgcn_s_setprio(1);                                           \
        _Pragma("unroll") for (int ks = 0; ks < 8; ++ks) {                       \
            bf16x8 pa = *(const bf16x8*)&Ps[wv][lr][ks * 32 + g * 8];            \
            _Pragma("unroll") for (int n = 0; n < 4; ++n) {                      \
                bf16x8 vb = *(const bf16x8*)&VPs[n * 16 + lr][ks * 32 + g * 8];  \
                o[n] = __builtin_amdgcn_mfma_f32_16x16x32_bf16(pa, vb, o[n], 0, 0, 0); \
            }                                                                    \
        }                                                                        \
        __builtin_amdgcn_s_setprio(0);                                           \
        __builtin_amdgcn_wave_barrier();                                         \
        _Pragma("unroll") for (int n = 0; n < 4; ++n)                            \
            _Pragma("unroll") for (int i = 0; i < 4; ++i)                        \
                Ps[wv][4 * g + i][n * 16 + lr] = (bf16)(o[n][i] * rs[i]);        \
        __builtin_amdgcn_wave_barrier();                                         \
        bf16* crow = ctx + (size_t)(b * SS + row0 + (IT) * 128) * DD + h * DK;   \
        _Pragma("unroll") for (int p = 0; p < 2; ++p) {                          \
            int r = p * 8 + (lane >> 3), c = (lane & 7) * 8;                     \
            bf16x8 ov = *(const bf16x8*)&Ps[wv][r][c];                           \
            *(bf16x8*)(crow + (size_t)r * DD + c) = ov;                          \
        }                                                                        \
        __builtin_amdgcn_wave_barrier();                                         \
        /* zero PC: it becomes the accumulator for iteration IT+2 */             \
        _Pragma("unroll") for (int nf = 0; nf < 16; ++nf)                        \
            PC[nf] = (f32x4){0.f, 0.f, 0.f, 0.f};                                \
        qa0 = qn0; qa1 = qn1;                                                    \
    }

    AITER(pA, pB, 0);
    AITER(pB, pA, 1);
    AITER(pA, pB, 2);
    AITER(pB, pA, 3);
    AITER(pA, pB, 4);
    AITER(pB, pA, 5);
    AITER(pA, pB, 6);
    AITER(pB, pA, 7);
#undef AITER
}

// ---------------------------------------------------------------------------
extern "C" void kernel_launch(void* const* d_in, const int* in_sizes, int n_in,
                              void* d_out, int out_size, void* d_ws, size_t ws_size,
                              hipStream_t stream)
{
    const float* query = (const float*)d_in[0];
    const float* key   = (const float*)d_in[1];
    const float* value = (const float*)d_in[2];
    const float* Wq = (const float*)d_in[3];  const float* bq = (const float*)d_in[4];
    const float* Wk = (const float*)d_in[5];  const float* bk = (const float*)d_in[6];
    const float* Wv = (const float*)d_in[7];  const float* bv = (const float*)d_in[8];
    const float* Wo = (const float*)d_in[9];  const float* bo = (const float*)d_in[10];
    const float* E  = (const float*)d_in[11];
    const float* F  = (const float*)d_in[12];

    char* w = (char*)d_ws;
    size_t off = 0;
    auto alloc = [&](size_t bytes) -> char* {
        char* p = w + off;
        off += (bytes + 255) & ~(size_t)255;
        return p;
    };

    const size_t DW   = (size_t)DD * DD;           // 1M
    const size_t BSD  = (size_t)BB * SS * DD;      // 16.78M
    const size_t BHDR = (size_t)BB * HH * DK * RR; // 4.19M

    bf16* wqb = (bf16*)alloc(DW * 2);
    bf16* wkb = (bf16*)alloc(DW * 2);
    bf16* wvb = (bf16*)alloc(DW * 2);
    bf16* wob = (bf16*)alloc(DW * 2);
    bf16* qin = (bf16*)alloc(BSD * 2);             // bf16 inputs; later reused:
    bf16* kin = (bf16*)alloc(BSD * 2);             //   qin -> kpf/vpf, kin -> kpt/vp,
    bf16* vin = (bf16*)alloc(BSD * 2);             //   vin -> ctx
    bf16* qbuf = (bf16*)alloc(BSD * 2);
    bf16* kbuf = (bf16*)alloc(BSD * 2);
    bf16* vbuf = (bf16*)alloc(BSD * 2);
    if (off > ws_size) return;

    // aliased scratch (stream-ordered reuse; regions dead by first write)
    float* kpf  = (float*)qin;                     // BHDR f32
    float* vpf  = kpf + BHDR;                      // BHDR f32
    bf16*  kpt  = (bf16*)kin;                      // BHDR bf16 [B,H,R,DK]
    bf16*  vpbb = kpt + BHDR;                      // BHDR bf16 [B,H,DK,R]
    bf16*  ctx  = (bf16*)vin;                      // BSD bf16

    // 1. converts: weights + activations
    cvt_f32_bf16<<<(int)(DW / 2048), 256, 0, stream>>>(Wq, wqb, (int)DW);
    cvt_f32_bf16<<<(int)(DW / 2048), 256, 0, stream>>>(Wk, wkb, (int)DW);
    cvt_f32_bf16<<<(int)(DW / 2048), 256, 0, stream>>>(Wv, wvb, (int)DW);
    cvt_f32_bf16<<<(int)(DW / 2048), 256, 0, stream>>>(Wo, wob, (int)DW);
    cvt_f32_bf16<<<(int)(BSD / 2048), 256, 0, stream>>>(query, qin, (int)BSD);
    cvt_f32_bf16<<<(int)(BSD / 2048), 256, 0, stream>>>(key,   kin, (int)BSD);
    cvt_f32_bf16<<<(int)(BSD / 2048), 256, 0, stream>>>(value, vin, (int)BSD);

    // 2. QKV projections (256x128 co-resident GEMM; q pre-scaled for exp2)
    const int nwg = ((BB * SS) / 256) * (DD / 128);   // 64*8 = 512, % 8 == 0
    gemm_bt<false><<<nwg, 512, 0, stream>>>(qin, wqb, bq, qbuf, BB * SS, DD, DD, QSCALE);
    gemm_bt<false><<<nwg, 512, 0, stream>>>(kin, wkb, bk, kbuf, BB * SS, DD, DD, 1.0f);
    gemm_bt<false><<<nwg, 512, 0, stream>>>(vin, wvb, bv, vbuf, BB * SS, DD, DD, 1.0f);

    // 3. kp/vp = k^T E, v^T F — E/F read directly as f32 (fused transpose+cvt)
    //    (qin region now dead -> kpf/vpf)
    hipMemsetAsync(kpf, 0, BHDR * 4 * 2, stream);
    kpvp_gemm<<<dim3(SS / 512, HH, BB), 256, 0, stream>>>(kbuf, E, kpf);
    kpvp_gemm<<<dim3(SS / 512, HH, BB), 256, 0, stream>>>(vbuf, F, vpf);

    // 4. kp -> kpT bf16 [B,H,R,DK]; vp -> bf16 [B,H,DK,R]  (kin region dead)
    dim3 tb(64, 4);
    transpose_cvt<<<dim3(RR / 64, DK / 64, BB * HH), tb, 0, stream>>>(kpf, kpt, DK, RR);
    cvt_f32_bf16<<<(int)(BHDR / 2048), 256, 0, stream>>>(vpf, vpbb, (int)BHDR);

    // 5. fused softmax attention (vin region dead -> ctx)
    attn_fused<<<dim3(SS / 1024, HH, BB), 512, 0, stream>>>(qbuf, kpt, vpbb, ctx);

    // 6. output projection -> f32 d_out
    gemm_bt<true><<<nwg, 512, 0, stream>>>(ctx, wob, bo, d_out, BB * SS, DD, DD, 1.0f);
}

// Round 10
// 384.932 us; speedup vs baseline: 1.1575x; 1.0071x over previous
//
#include <hip/hip_runtime.h>

// ---------------------------------------------------------------------------
// LinearAttention (Linformer-style) on MI355X, bf16 MFMA pipeline, f32 accum.
// B=4 S=4096 D=1024 H=16 R=256 DK=64
// Round 10: REVERT attn to the round-8 single-accumulator structure (57us;
//           the round-9 T15 2-deep pipeline spilled and ran 2x slow — m253's
//           documented regime). Keep kpvp-v2 (direct f32 E/F) and round-8
//           gemm_bt (frozen).
// ---------------------------------------------------------------------------

typedef __bf16 bf16;
typedef bf16 bf16x8 __attribute__((ext_vector_type(8)));
typedef bf16 bf16x4 __attribute__((ext_vector_type(4)));
typedef float f32x4 __attribute__((ext_vector_type(4)));

constexpr int BB = 4, SS = 4096, DD = 1024, HH = 16, RR = 256, DK = 64;

// q-projection output pre-scale: logits*log2e/8 so softmax uses exp2 directly
#define QSCALE 0.1803368801111204f

// async global->LDS, 16B per lane. ldsbase must be wave-uniform; HW writes
// lane l's 16B at ldsbase + l*16. gptr is per-lane.
__device__ __forceinline__ void gl2lds16(const void* g, void* l, int lane)
{
#if __has_builtin(__builtin_amdgcn_global_load_lds)
    auto gp = reinterpret_cast<const __attribute__((address_space(1))) void*>(
        reinterpret_cast<uintptr_t>(g));
    auto lp = reinterpret_cast<__attribute__((address_space(3))) void*>(
        reinterpret_cast<uintptr_t>(l));
    __builtin_amdgcn_global_load_lds(gp, lp, 16, 0, 0);
    (void)lane;
#else
    *(bf16x8*)((char*)l + lane * 16) = *(const bf16x8*)g;
#endif
}

#define VMW3  asm volatile("s_waitcnt vmcnt(3)" ::: "memory")
#define VMW0  asm volatile("s_waitcnt vmcnt(0)" ::: "memory")
#define LGKM0 asm volatile("s_waitcnt lgkmcnt(0)" ::: "memory")

// ---------------------------------------------------------------------------
// Elementwise f32 -> bf16 convert, 8 elems/thread
// ---------------------------------------------------------------------------
__global__ void cvt_f32_bf16(const float* __restrict__ in, bf16* __restrict__ out, int n)
{
    int i = (blockIdx.x * 256 + threadIdx.x) * 8;
    if (i < n) {
        float4 v0 = *(const float4*)(in + i);
        float4 v1 = *(const float4*)(in + i + 4);
        bf16x8 h;
        h[0] = (bf16)v0.x; h[1] = (bf16)v0.y; h[2] = (bf16)v0.z; h[3] = (bf16)v0.w;
        h[4] = (bf16)v1.x; h[5] = (bf16)v1.y; h[6] = (bf16)v1.z; h[7] = (bf16)v1.w;
        *(bf16x8*)(out + i) = h;
    }
}

// ---------------------------------------------------------------------------
// Tiled transpose + convert (used for kp f32 [DK,R] -> kpT bf16 [R,DK])
// ---------------------------------------------------------------------------
__global__ void transpose_cvt(const float* __restrict__ in, bf16* __restrict__ out,
                              int rows, int cols)
{
    __shared__ float t[64][65];
    const float* I = in + (size_t)blockIdx.z * rows * cols;
    bf16* O = out + (size_t)blockIdx.z * rows * cols;
    int c0 = blockIdx.x * 64, r0 = blockIdx.y * 64;
    int tx = threadIdx.x, ty = threadIdx.y;
#pragma unroll
    for (int i = ty; i < 64; i += 4)
        t[i][tx] = I[(size_t)(r0 + i) * cols + c0 + tx];
    __syncthreads();
#pragma unroll
    for (int i = ty; i < 64; i += 4)
        O[(size_t)(c0 + i) * rows + r0 + tx] = (bf16)t[tx][i];
}

// ---------------------------------------------------------------------------
// C[M,N] = (A[M,K](bf16) * W[N,K]^T(bf16) + bias[N]) * oscale.   K == 1024.
// Round-8 structure (frozen): 256x128 tile, BK=32, 8 waves (4M x 2N), 48KB LDS
// -> co-resident blocks; counted VMW3; 64B-row swizzle.
// ---------------------------------------------------------------------------
template <bool OUT_F32>
__global__ __launch_bounds__(512, 4) void gemm_bt(const bf16* __restrict__ A,
                                                  const bf16* __restrict__ W,
                                                  const float* __restrict__ bias,
                                                  void* __restrict__ Cp,
                                                  int M, int N, int K, float oscale)
{
    __shared__ bf16 As[2][256][32];
    __shared__ bf16 Bs[2][128][32];
    const int tid = threadIdx.x, wv = tid >> 6, lane = tid & 63;
    const int g = lane >> 4, lr = lane & 15;

    const int nwg = gridDim.x;
    const int cpx = nwg >> 3;                      // nwg % 8 == 0 (bijective)
    const int bid = blockIdx.x;
    const int swz = (bid & 7) * cpx + (bid >> 3);
    const int gx = N >> 7;
    const int mt = swz / gx, nt = swz % gx;
    const int m0 = mt * 256, n0 = nt * 128;
    const int wm = (wv >> 1) * 64, wn = (wv & 1) * 64;

    const int srow = lane >> 2;
    const int scol = ((lane & 3) ^ ((lane >> 4) & 3)) * 8;

    f32x4 acc[4][4] = {};

    auto stageA = [&](int buf, int tk) {
#pragma unroll
        for (int s2 = 0; s2 < 2; ++s2) {
            int c = wv * 2 + s2;
            gl2lds16(A + (size_t)(m0 + c * 16 + srow) * 1024 + tk * 32 + scol,
                     &As[buf][c * 16][0], lane);
        }
    };
    auto stageB = [&](int buf, int tk) {
        gl2lds16(W + (size_t)(n0 + wv * 16 + srow) * 1024 + tk * 32 + scol,
                 &Bs[buf][wv * 16][0], lane);
    };

#define PHK(PB, STAGE_STMT, VM_STMT)                                             \
    {                                                                            \
        const int so = (g ^ (lr >> 2)) << 4;                                     \
        bf16x8 aF[4], bF[4];                                                     \
        _Pragma("unroll") for (int mm = 0; mm < 4; ++mm)                         \
            aF[mm] = *(const bf16x8*)((const char*)&As[PB][wm + mm * 16 + lr][0] + so); \
        _Pragma("unroll") for (int nn = 0; nn < 4; ++nn)                         \
            bF[nn] = *(const bf16x8*)((const char*)&Bs[PB][wn + nn * 16 + lr][0] + so); \
        LGKM0;                                                                   \
        __builtin_amdgcn_s_barrier();              /* all waves' reads done */   \
        STAGE_STMT;                                /* overwrite buffer PB */     \
        VM_STMT;                                   /* drain tile t+1 */          \
        __builtin_amdgcn_s_barrier();              /* next buffer visible */     \
        __builtin_amdgcn_sched_barrier(0);                                       \
        __builtin_amdgcn_s_setprio(1);                                           \
        _Pragma("unroll") for (int mm = 0; mm < 4; ++mm) {                       \
            _Pragma("unroll") for (int nn = 0; nn < 4; ++nn) {                   \
                acc[mm][nn] = __builtin_amdgcn_mfma_f32_16x16x32_bf16(           \
                    aF[mm], bF[nn], acc[mm][nn], 0, 0, 0); } }                   \
        __builtin_amdgcn_s_setprio(0);                                           \
    }

    stageA(0, 0); stageB(0, 0);
    stageA(1, 1); stageB(1, 1);
    VMW3;
    __builtin_amdgcn_s_barrier();

#pragma unroll 1
    for (int t = 0; t < 30; ++t) {
        const int pb = t & 1;
        PHK(pb, { stageA(pb, t + 2); stageB(pb, t + 2); }, VMW3);
    }
    PHK(0, (void)0, VMW0);
    PHK(1, (void)0, (void)0);
#undef PHK

    float bv[4];
#pragma unroll
    for (int n = 0; n < 4; ++n) bv[n] = bias[n0 + wn + n * 16 + lr];

    if constexpr (OUT_F32) {
#pragma unroll
        for (int n = 0; n < 4; ++n) {
            int col = n0 + wn + n * 16 + lr;
#pragma unroll
            for (int m = 0; m < 4; ++m) {
                int row = m0 + wm + m * 16 + 4 * g;
#pragma unroll
                for (int i = 0; i < 4; ++i)
                    ((float*)Cp)[(size_t)(row + i) * N + col] = (acc[m][n][i] + bv[n]) * oscale;
            }
        }
    } else {
        char* myb = (char*)&As[0][0][0] + wv * 4096;
#pragma unroll
        for (int mh = 0; mh < 2; ++mh) {
#pragma unroll
            for (int mm = 0; mm < 2; ++mm)
#pragma unroll
                for (int n = 0; n < 4; ++n) {
                    int colb = (n * 16 + lr) * 2;
#pragma unroll
                    for (int i = 0; i < 4; ++i) {
                        int row = mm * 16 + 4 * g + i;
                        *(bf16*)(myb + row * 128 + (colb ^ ((row & 7) << 4))) =
                            (bf16)((acc[mh * 2 + mm][n][i] + bv[n]) * oscale);
                    }
                }
            __builtin_amdgcn_wave_barrier();
            bf16* Cb = (bf16*)Cp + (size_t)(m0 + wm + mh * 32) * N + n0 + wn;
#pragma unroll
            for (int it = 0; it < 4; ++it) {
                int r = it * 8 + (lane >> 3);
                int sl = lane & 7;
                bf16x8 vv = *(const bf16x8*)(myb + r * 128 + ((sl ^ (r & 7)) << 4));
                *(bf16x8*)(Cb + (size_t)r * N + sl * 8) = vv;
            }
            __builtin_amdgcn_wave_barrier();
        }
    }
}

// ---------------------------------------------------------------------------
// kp[b,h,d,r] += sum_{s in chunk} X[b,s,h*64+d] * E[h,s,r]
// E read DIRECTLY as f32 [H,S,R] (fused transpose+convert in registers).
// ---------------------------------------------------------------------------
__global__ __launch_bounds__(256) void kpvp_gemm(const bf16* __restrict__ X,
                                                 const float* __restrict__ E,
                                                 float* __restrict__ out)
{
    __shared__ bf16 Ak[64][40];
    const int b = blockIdx.z, h = blockIdx.y;
    const int s0 = blockIdx.x * 512;
    const int tid = threadIdx.x, wv = tid >> 6, lane = tid & 63;
    const int g = lane >> 4, lr = lane & 15;
    const float* Eh = E + (size_t)h * SS * RR;
    const int rbase = wv * 64 + lr;
    f32x4 acc[4][4] = {};

    for (int kt = 0; kt < 512; kt += 32) {
        const int sb = s0 + kt;
        __syncthreads();
        float ef[4][8];
        const float* Eb = Eh + (size_t)(sb + g * 8) * RR + rbase;
#pragma unroll
        for (int n = 0; n < 4; ++n)
#pragma unroll
            for (int j = 0; j < 8; ++j)
                ef[n][j] = Eb[(size_t)j * RR + n * 16];
        {   // A-stage with transpose: X[b, sb+sl, h*64+dblk+j] -> Ak[dblk+j][sl]
            int sl = tid >> 3, dblk = (tid & 7) * 8;
            bf16x8 v = *(const bf16x8*)(X + ((size_t)b * SS + sb + sl) * DD + h * DK + dblk);
#pragma unroll
            for (int j = 0; j < 8; ++j) Ak[dblk + j][sl] = v[j];
        }
        bf16x8 bb[4];
#pragma unroll
        for (int n = 0; n < 4; ++n)
#pragma unroll
            for (int j = 0; j < 8; ++j)
                bb[n][j] = (bf16)ef[n][j];
        __syncthreads();

        bf16x8 a[4];
#pragma unroll
        for (int m = 0; m < 4; ++m) a[m] = *(const bf16x8*)&Ak[m * 16 + lr][g * 8];
#pragma unroll
        for (int m = 0; m < 4; ++m)
#pragma unroll
            for (int n = 0; n < 4; ++n)
                acc[m][n] = __builtin_amdgcn_mfma_f32_16x16x32_bf16(a[m], bb[n], acc[m][n], 0, 0, 0);
    }

    float* o = out + ((size_t)(b * HH + h)) * DK * RR;
#pragma unroll
    for (int m = 0; m < 4; ++m)
#pragma unroll
        for (int n = 0; n < 4; ++n) {
            int r = wv * 64 + n * 16 + lr;
#pragma unroll
            for (int i = 0; i < 4; ++i)
                atomicAdd(o + (size_t)(m * 16 + 4 * g + i) * RR + r, acc[m][n][i]);
        }
}

// ---------------------------------------------------------------------------
// Fused attention (round-8 structure, measured 57us): 256 blocks x 8 waves,
// single accumulator, KP/VP staged once, barrier-free inner loop, exp2
// softmax, deferred norm, LDS-bounced coalesced ctx stores.
// ---------------------------------------------------------------------------
__global__ __launch_bounds__(512) void attn_fused(const bf16* __restrict__ qb,
                                                  const bf16* __restrict__ kpt,
                                                  const bf16* __restrict__ vpb,
                                                  bf16* __restrict__ ctx)
{
    __shared__ bf16 KPs[256][72];      // kpT tile [r][d]
    __shared__ bf16 VPs[64][264];      // vp tile [d][r]
    __shared__ bf16 Ps[8][16][264];    // per-wave P / out-bounce tile
    const int b = blockIdx.z, h = blockIdx.y, qt = blockIdx.x;
    const int tid = threadIdx.x, wv = tid >> 6, lane = tid & 63;
    const int g = lane >> 4, lr = lane & 15;
    const bf16* kph = kpt + ((size_t)(b * HH + h)) * RR * DK;
    const bf16* vph = vpb + ((size_t)(b * HH + h)) * DK * RR;

#pragma unroll
    for (int p = 0; p < 4; ++p) {
        int f = p * 512 + tid;
        *(bf16x8*)&KPs[f >> 3][(f & 7) * 8] = *(const bf16x8*)(kph + (size_t)f * 8);
        *(bf16x8*)&VPs[f >> 5][(f & 31) * 8] = *(const bf16x8*)(vph + (size_t)f * 8);
    }

    const bf16* qbase = qb + (size_t)b * SS * DD + h * DK;
    int row0 = qt * 1024 + wv * 16;
    bf16x8 aq0 = *(const bf16x8*)(qbase + (size_t)(row0 + lr) * DD + g * 8);
    bf16x8 aq1 = *(const bf16x8*)(qbase + (size_t)(row0 + lr) * DD + 32 + g * 8);
    __syncthreads();

    for (int it = 0; it < 8; ++it) {
        f32x4 acc[16] = {};
        __builtin_amdgcn_s_setprio(1);
#pragma unroll
        for (int nf = 0; nf < 16; ++nf) {
            bf16x8 b0 = *(const bf16x8*)&KPs[nf * 16 + lr][g * 8];
            bf16x8 b1 = *(const bf16x8*)&KPs[nf * 16 + lr][32 + g * 8];
            acc[nf] = __builtin_amdgcn_mfma_f32_16x16x32_bf16(aq0, b0, acc[nf], 0, 0, 0);
            acc[nf] = __builtin_amdgcn_mfma_f32_16x16x32_bf16(aq1, b1, acc[nf], 0, 0, 0);
        }
        __builtin_amdgcn_s_setprio(0);

        bf16x8 aqn0 = aq0, aqn1 = aq1;
        if (it < 7) {
            const bf16* qr = qbase + (size_t)(row0 + 128 + lr) * DD;
            aqn0 = *(const bf16x8*)(qr + g * 8);
            aqn1 = *(const bf16x8*)(qr + 32 + g * 8);
        }

        float rs[4];
#pragma unroll
        for (int i = 0; i < 4; ++i) {
            float s = 0.f;
#pragma unroll
            for (int nf = 0; nf < 16; ++nf) {
                float pv = exp2f(acc[nf][i]);
                acc[nf][i] = pv;
                s += pv;
            }
#pragma unroll
            for (int msk = 1; msk < 16; msk <<= 1) s += __shfl_xor(s, msk, 64);
            rs[i] = 1.f / s;
        }

#pragma unroll
        for (int nf = 0; nf < 16; ++nf)
#pragma unroll
            for (int i = 0; i < 4; ++i)
                Ps[wv][4 * g + i][nf * 16 + lr] = (bf16)acc[nf][i];
        __builtin_amdgcn_wave_barrier();

        f32x4 o[4] = {};
        __builtin_amdgcn_s_setprio(1);
#pragma unroll
        for (int ks = 0; ks < 8; ++ks) {
            bf16x8 pa = *(const bf16x8*)&Ps[wv][lr][ks * 32 + g * 8];
#pragma unroll
            for (int n = 0; n < 4; ++n) {
                bf16x8 vb = *(const bf16x8*)&VPs[n * 16 + lr][ks * 32 + g * 8];
                o[n] = __builtin_amdgcn_mfma_f32_16x16x32_bf16(pa, vb, o[n], 0, 0, 0);
            }
        }
        __builtin_amdgcn_s_setprio(0);
        __builtin_amdgcn_wave_barrier();

#pragma unroll
        for (int n = 0; n < 4; ++n)
#pragma unroll
            for (int i = 0; i < 4; ++i)
                Ps[wv][4 * g + i][n * 16 + lr] = (bf16)(o[n][i] * rs[i]);
        __builtin_amdgcn_wave_barrier();
        bf16* crow = ctx + (size_t)(b * SS + row0) * DD + h * DK;
#pragma unroll
        for (int p = 0; p < 2; ++p) {
            int r = p * 8 + (lane >> 3), c = (lane & 7) * 8;
            bf16x8 ov = *(const bf16x8*)&Ps[wv][r][c];
            *(bf16x8*)(crow + (size_t)r * DD + c) = ov;
        }
        __builtin_amdgcn_wave_barrier();

        aq0 = aqn0; aq1 = aqn1;
        row0 += 128;
    }
}

// ---------------------------------------------------------------------------
extern "C" void kernel_launch(void* const* d_in, const int* in_sizes, int n_in,
                              void* d_out, int out_size, void* d_ws, size_t ws_size,
                              hipStream_t stream)
{
    const float* query = (const float*)d_in[0];
    const float* key   = (const float*)d_in[1];
    const float* value = (const float*)d_in[2];
    const float* Wq = (const float*)d_in[3];  const float* bq = (const float*)d_in[4];
    const float* Wk = (const float*)d_in[5];  const float* bk = (const float*)d_in[6];
    const float* Wv = (const float*)d_in[7];  const float* bv = (const float*)d_in[8];
    const float* Wo = (const float*)d_in[9];  const float* bo = (const float*)d_in[10];
    const float* E  = (const float*)d_in[11];
    const float* F  = (const float*)d_in[12];

    char* w = (char*)d_ws;
    size_t off = 0;
    auto alloc = [&](size_t bytes) -> char* {
        char* p = w + off;
        off += (bytes + 255) & ~(size_t)255;
        return p;
    };

    const size_t DW   = (size_t)DD * DD;           // 1M
    const size_t BSD  = (size_t)BB * SS * DD;      // 16.78M
    const size_t BHDR = (size_t)BB * HH * DK * RR; // 4.19M

    bf16* wqb = (bf16*)alloc(DW * 2);
    bf16* wkb = (bf16*)alloc(DW * 2);
    bf16* wvb = (bf16*)alloc(DW * 2);
    bf16* wob = (bf16*)alloc(DW * 2);
    bf16* qin = (bf16*)alloc(BSD * 2);             // bf16 inputs; later reused:
    bf16* kin = (bf16*)alloc(BSD * 2);             //   qin -> kpf/vpf, kin -> kpt/vp,
    bf16* vin = (bf16*)alloc(BSD * 2);             //   vin -> ctx
    bf16* qbuf = (bf16*)alloc(BSD * 2);
    bf16* kbuf = (bf16*)alloc(BSD * 2);
    bf16* vbuf = (bf16*)alloc(BSD * 2);
    if (off > ws_size) return;

    // aliased scratch (stream-ordered reuse; regions dead by first write)
    float* kpf  = (float*)qin;                     // BHDR f32
    float* vpf  = kpf + BHDR;                      // BHDR f32
    bf16*  kpt  = (bf16*)kin;                      // BHDR bf16 [B,H,R,DK]
    bf16*  vpbb = kpt + BHDR;                      // BHDR bf16 [B,H,DK,R]
    bf16*  ctx  = (bf16*)vin;                      // BSD bf16

    // 1. converts: weights + activations
    cvt_f32_bf16<<<(int)(DW / 2048), 256, 0, stream>>>(Wq, wqb, (int)DW);
    cvt_f32_bf16<<<(int)(DW / 2048), 256, 0, stream>>>(Wk, wkb, (int)DW);
    cvt_f32_bf16<<<(int)(DW / 2048), 256, 0, stream>>>(Wv, wvb, (int)DW);
    cvt_f32_bf16<<<(int)(DW / 2048), 256, 0, stream>>>(Wo, wob, (int)DW);
    cvt_f32_bf16<<<(int)(BSD / 2048), 256, 0, stream>>>(query, qin, (int)BSD);
    cvt_f32_bf16<<<(int)(BSD / 2048), 256, 0, stream>>>(key,   kin, (int)BSD);
    cvt_f32_bf16<<<(int)(BSD / 2048), 256, 0, stream>>>(value, vin, (int)BSD);

    // 2. QKV projections (256x128 co-resident GEMM; q pre-scaled for exp2)
    const int nwg = ((BB * SS) / 256) * (DD / 128);   // 64*8 = 512, % 8 == 0
    gemm_bt<false><<<nwg, 512, 0, stream>>>(qin, wqb, bq, qbuf, BB * SS, DD, DD, QSCALE);
    gemm_bt<false><<<nwg, 512, 0, stream>>>(kin, wkb, bk, kbuf, BB * SS, DD, DD, 1.0f);
    gemm_bt<false><<<nwg, 512, 0, stream>>>(vin, wvb, bv, vbuf, BB * SS, DD, DD, 1.0f);

    // 3. kp/vp = k^T E, v^T F — E/F read directly as f32 (fused transpose+cvt)
    hipMemsetAsync(kpf, 0, BHDR * 4 * 2, stream);
    kpvp_gemm<<<dim3(SS / 512, HH, BB), 256, 0, stream>>>(kbuf, E, kpf);
    kpvp_gemm<<<dim3(SS / 512, HH, BB), 256, 0, stream>>>(vbuf, F, vpf);

    // 4. kp -> kpT bf16 [B,H,R,DK]; vp -> bf16 [B,H,DK,R]  (kin region dead)
    dim3 tb(64, 4);
    transpose_cvt<<<dim3(RR / 64, DK / 64, BB * HH), tb, 0, stream>>>(kpf, kpt, DK, RR);
    cvt_f32_bf16<<<(int)(BHDR / 2048), 256, 0, stream>>>(vpf, vpbb, (int)BHDR);

    // 5. fused softmax attention (vin region dead -> ctx)
    attn_fused<<<dim3(SS / 1024, HH, BB), 512, 0, stream>>>(qbuf, kpt, vpbb, ctx);

    // 6. output projection -> f32 d_out
    gemm_bt<true><<<nwg, 512, 0, stream>>>(ctx, wob, bo, d_out, BB * SS, DD, DD, 1.0f);
}